// Round 11
// baseline (101.058 us; speedup 1.0000x reference)
//
#include <hip/hip_runtime.h>
#include <math.h>

#define LL 1024
#define DD 640
#define KK 32
#define MM 64
#define THRESH 0.2f
#define LOG2E 1.4426950408889634f

// ws layout (float units)
#define NPROJ_OFF  0                        // [1024][64] node_proj + b_edge (backbone base)
#define NPROJC_OFF (NPROJ_OFF + LL * MM)    // [1024][64] node_proj + b_edge + W0 (contact base)
#define WRT_OFF    (NPROJC_OFF + LL * MM)   // ushort[64][32]: bf16 W_edge[2+k][m], m-major
#define W1_OFF     (WRT_OFF + 1024)         // 64 f32
#define EA_OFF     (W1_OFF + MM)            // 32 f32 : -log2e/(2 sigma^2)
#define EB_OFF     (EA_OFF + KK)            // 32 f32 :  log2e*mu/sigma^2
#define EC_OFF     (EB_OFF + KK)            // 32 f32 : -log2e*mu^2/(2 sigma^2)
#define XYZ4_OFF   (EC_OFF + KK)            // [1024][4] padded coords

typedef float f32x4_t __attribute__((ext_vector_type(4)));
typedef short bf16x8_t __attribute__((ext_vector_type(8)));

union FragU { unsigned int u[4]; bf16x8_t v; };

#if __has_builtin(__builtin_amdgcn_sqrtf)
#define FSQRT __builtin_amdgcn_sqrtf
#else
#define FSQRT sqrtf
#endif

#if __has_builtin(__builtin_amdgcn_exp2f)
#define EXP2F __builtin_amdgcn_exp2f
#else
#define EXP2F(x) __expf((x) * 0.6931471805599453f)
#endif

__device__ __forceinline__ unsigned int pack_bf(float hi, float lo) {
    return __builtin_amdgcn_perm(__float_as_uint(hi), __float_as_uint(lo), 0x07060302u);
}

// Split-K node_proj GEMM (r10) + constants block also initializes out = xyz.
__global__ __launch_bounds__(256) void prep_sk(
    const float* __restrict__ S, const float* __restrict__ xyz,
    const float* __restrict__ rbf_mu, const float* __restrict__ rbf_sigma,
    const float* __restrict__ W_edge, const float* __restrict__ b_edge,
    const float* __restrict__ W_node, float* __restrict__ ws,
    float* __restrict__ out)
{
    const int b = blockIdx.x;
    const int t = threadIdx.x;
    if (b < 256) {
        __shared__ float red[4][64][4];
        const int lane = t & 63;
        const int wave = t >> 6;
        const int r0   = (b >> 2) * 16;     // row tile
        const int n0   = (b & 3) * 16;      // col tile
        const int col  = lane & 15;
        const int quad = lane >> 4;

        f32x4_t acc = {0.f, 0.f, 0.f, 0.f};
        const float* arow = S + (size_t)(r0 + col) * DD + wave * 160 + quad * 8;
        const float* bcol = W_node + (size_t)(wave * 160 + quad * 8) * MM + n0 + col;

        #pragma unroll
        for (int ks = 0; ks < 5; ++ks) {
            const float4 a0 = *(const float4*)(arow + ks * 32);
            const float4 a1 = *(const float4*)(arow + ks * 32 + 4);
            FragU A;
            A.u[0] = pack_bf(a0.y, a0.x); A.u[1] = pack_bf(a0.w, a0.z);
            A.u[2] = pack_bf(a1.y, a1.x); A.u[3] = pack_bf(a1.w, a1.z);
            const float* bk = bcol + (size_t)ks * 32 * MM;
            const float b0 = bk[0 * MM], b1 = bk[1 * MM], b2 = bk[2 * MM], b3 = bk[3 * MM];
            const float b4 = bk[4 * MM], b5 = bk[5 * MM], b6 = bk[6 * MM], b7 = bk[7 * MM];
            FragU B;
            B.u[0] = pack_bf(b1, b0); B.u[1] = pack_bf(b3, b2);
            B.u[2] = pack_bf(b5, b4); B.u[3] = pack_bf(b7, b6);
            acc = __builtin_amdgcn_mfma_f32_16x16x32_bf16(A.v, B.v, acc, 0, 0, 0);
        }
        red[wave][lane][0] = acc[0];
        red[wave][lane][1] = acc[1];
        red[wave][lane][2] = acc[2];
        red[wave][lane][3] = acc[3];
        __syncthreads();
        const int lr  = t & 63;
        const int reg = t >> 6;
        const float v = (red[0][lr][reg] + red[1][lr][reg])
                      + (red[2][lr][reg] + red[3][lr][reg]);
        const int row = r0 + (lr >> 4) * 4 + reg;
        const int cc  = n0 + (lr & 15);
        const float vb = v + b_edge[cc];
        ws[NPROJ_OFF  + (size_t)row * MM + cc] = vb;
        ws[NPROJC_OFF + (size_t)row * MM + cc] = vb + W_edge[cc];
    } else {
        unsigned short* wrt = (unsigned short*)(ws + WRT_OFF);
        if (t < MM) ws[W1_OFF + t] = W_edge[MM + t];
        if (t < KK) {
            const float s  = rbf_sigma[t];
            const float m_ = rbf_mu[t];
            const float inv = 1.0f / (2.0f * s * s);
            ws[EA_OFF + t] = -LOG2E * inv;
            ws[EB_OFF + t] =  2.0f * LOG2E * inv * m_;
            ws[EC_OFF + t] = -LOG2E * inv * m_ * m_;
        }
        for (int idx = t; idx < KK * MM; idx += 256) {
            const int m = idx >> 5, k = idx & 31;
            unsigned int u = __float_as_uint(W_edge[(2 + k) * MM + m]);
            u = (u + 0x7fffu + ((u >> 16) & 1u)) >> 16;   // RNE to bf16
            wrt[idx] = (unsigned short)u;
        }
        for (int n = t; n < LL; n += 256) {
            float4 v;
            v.x = xyz[3 * n + 0]; v.y = xyz[3 * n + 1];
            v.z = xyz[3 * n + 2]; v.w = 0.0f;
            *(float4*)(ws + XYZ4_OFF + 4 * n) = v;
        }
        // out init: edge blocks atomically accumulate on top of xyz
        for (int idx = t; idx < 3 * LL; idx += 256) out[idx] = xyz[idx];
    }
}

// Balanced half-row pairing: 1024 blocks x 256 thr. Block b processes
// row b's FIRST half + row (1023-b)'s SECOND half (~511 edges each) so all
// blocks stay resident to a simultaneous finish (kills the triangular drain).
// Per-row partials combined via 3 atomicAdds onto out (pre-init = xyz).
__global__ __launch_bounds__(256, 4) void edge_kernel5(
    const float* __restrict__ P, const float* __restrict__ w_out,
    const float* __restrict__ ws, float* __restrict__ out)
{
    const int tid  = threadIdx.x;
    const int lane = tid & 63;
    const int wave = tid >> 6;
    const int quad = lane >> 4;
    const int col  = lane & 15;
    __shared__ float sred[4][3];

    const float* __restrict__ nproj  = ws + NPROJ_OFF;
    const float* __restrict__ nprojc = ws + NPROJC_OFF;
    const float4* __restrict__ xyz4  = (const float4*)(ws + XYZ4_OFF);
    const unsigned short* __restrict__ wrt = (const unsigned short*)(ws + WRT_OFF);

    // persistent frags (serial-ct body: proven ~80 VGPR)
    FragU ar[4];
    float w1r[16], wvr[16];
    float aj[8], bj[8], cj[8];
    #pragma unroll
    for (int mt = 0; mt < 4; ++mt) {
        const uint4 w = *(const uint4*)(wrt + (mt * 16 + col) * KK + quad * 8);
        ar[mt].u[0] = w.x; ar[mt].u[1] = w.y; ar[mt].u[2] = w.z; ar[mt].u[3] = w.w;
        const f32x4_t w1 = *(const f32x4_t*)(ws + W1_OFF + mt * 16 + quad * 4);
        const f32x4_t wo = *(const f32x4_t*)(w_out + mt * 16 + quad * 4);
        #pragma unroll
        for (int r = 0; r < 4; ++r) { w1r[mt * 4 + r] = w1[r]; wvr[mt * 4 + r] = wo[r]; }
    }
    #pragma unroll
    for (int j = 0; j < 8; ++j) {
        aj[j] = ws[EA_OFF + quad * 8 + j];
        bj[j] = ws[EB_OFF + quad * 8 + j];
        cj[j] = ws[EC_OFF + quad * 8 + j];
    }

    const int b = (int)blockIdx.x;

    #pragma unroll 1
    for (int ss = 0; ss < 2; ++ss) {
        // segment: ss=0 -> row b, jo in [0, h); ss=1 -> row 1023-b, jo in [h2, len)
        int i, s0, s1;
        if (ss == 0) {
            i = b;
            const int len = (LL - 1) - b;
            s0 = 0; s1 = (len + 1) >> 1;
        } else {
            i = (LL - 1) - b;
            const int len = b;
            s0 = (len + 1) >> 1; s1 = len;
        }
        const float4 xo = xyz4[i];
        const float xi0 = xo.x, xi1 = xo.y, xi2 = xo.z;
        float ax = 0.f, ay = 0.f, az = 0.f;
        const float* __restrict__ prow = P + (size_t)i * LL;

        for (int base = s0 + wave * 64; base < s1; base += 256) {
            // own edge
            const int jo = base + lane;
            const bool valid = jo < s1;
            const int jc_o = valid ? (i + 1 + jo) : (LL - 1);
            const float p_own = prow[jc_o];
            const float4 xj = xyz4[jc_o];
            const float rx = xj.x - xi0, ry = xj.y - xi1, rz = xj.z - xi2;
            const bool msk = valid && ((jo == 0) || ((jo >= 2) && (p_own > THRESH)));

            float res[4];
            #pragma unroll
            for (int ct = 0; ct < 4; ++ct) {
                const int jo_n = base + ct * 16 + col;
                int jc = i + 1 + jo_n;
                jc = (jc < LL) ? jc : (LL - 1);
                const float p_n = prow[jc];
                const float4 xn = xyz4[jc];
                const float dx = xn.x - xi0, dy = xn.y - xi1, dz = xn.z - xi2;
                const float q2 = fmaf(dx, dx, fmaf(dy, dy, fmaf(dz, dz, 1e-12f)));
                const float d_n = FSQRT(q2);
                const bool bb = (jo_n == 0);
                const float peff = bb ? 1.0f : p_n;
                const float* npr = (bb ? nproj : nprojc) + (size_t)jc * MM;

                float e[8];
                #pragma unroll
                for (int j = 0; j < 8; ++j)
                    e[j] = EXP2F(fmaf(aj[j], q2, fmaf(bj[j], d_n, cj[j])));
                FragU bf;
                bf.u[0] = pack_bf(e[1], e[0]); bf.u[1] = pack_bf(e[3], e[2]);
                bf.u[2] = pack_bf(e[5], e[4]); bf.u[3] = pack_bf(e[7], e[6]);

                float g = 0.0f;
                #pragma unroll
                for (int mt = 0; mt < 4; ++mt) {
                    f32x4_t c0 = *(const f32x4_t*)(npr + mt * 16 + quad * 4);
                    c0[0] = fmaf(peff, w1r[mt*4+0], c0[0]);
                    c0[1] = fmaf(peff, w1r[mt*4+1], c0[1]);
                    c0[2] = fmaf(peff, w1r[mt*4+2], c0[2]);
                    c0[3] = fmaf(peff, w1r[mt*4+3], c0[3]);
                    c0 = __builtin_amdgcn_mfma_f32_16x16x32_bf16(ar[mt].v, bf.v, c0, 0, 0, 0);
                    g = fmaf(fmaxf(c0[0], 0.f), wvr[mt*4+0], g);
                    g = fmaf(fmaxf(c0[1], 0.f), wvr[mt*4+1], g);
                    g = fmaf(fmaxf(c0[2], 0.f), wvr[mt*4+2], g);
                    g = fmaf(fmaxf(c0[3], 0.f), wvr[mt*4+3], g);
                }
                g += __shfl_xor(g, 16, 64);
                g += __shfl_xor(g, 32, 64);
                res[ct] = g;
            }
            float gd = res[0];
            gd = (quad == 1) ? res[1] : gd;
            gd = (quad == 2) ? res[2] : gd;
            gd = (quad == 3) ? res[3] : gd;
            const float gate = msk ? (1.0f / (1.0f + __expf(-gd))) : 0.0f;
            ax = fmaf(gate, rx, ax);
            ay = fmaf(gate, ry, ay);
            az = fmaf(gate, rz, az);
        }

        // reduce 64 lanes then 4 waves; one atomic triple per (block, row)
        #pragma unroll
        for (int off = 32; off > 0; off >>= 1) {
            ax += __shfl_down(ax, off, 64);
            ay += __shfl_down(ay, off, 64);
            az += __shfl_down(az, off, 64);
        }
        if (lane == 0) { sred[wave][0] = ax; sred[wave][1] = ay; sred[wave][2] = az; }
        __syncthreads();
        if (tid == 0) {
            const float tx = (sred[0][0] + sred[1][0]) + (sred[2][0] + sred[3][0]);
            const float ty = (sred[0][1] + sred[1][1]) + (sred[2][1] + sred[3][1]);
            const float tz = (sred[0][2] + sred[1][2]) + (sred[2][2] + sred[3][2]);
            atomicAdd(out + i * 3 + 0, tx);
            atomicAdd(out + i * 3 + 1, ty);
            atomicAdd(out + i * 3 + 2, tz);
        }
        __syncthreads();   // protect sred before next segment
    }
}

extern "C" void kernel_launch(void* const* d_in, const int* in_sizes, int n_in,
                              void* d_out, int out_size, void* d_ws, size_t ws_size,
                              hipStream_t stream) {
    const float* S         = (const float*)d_in[0];
    const float* P         = (const float*)d_in[1];
    const float* xyz       = (const float*)d_in[2];
    const float* rbf_mu    = (const float*)d_in[3];
    const float* rbf_sigma = (const float*)d_in[4];
    const float* W_edge    = (const float*)d_in[5];
    const float* b_edge    = (const float*)d_in[6];
    const float* W_node    = (const float*)d_in[7];
    const float* w_out     = (const float*)d_in[8];
    float* out = (float*)d_out;
    float* ws  = (float*)d_ws;

    prep_sk<<<257, 256, 0, stream>>>(S, xyz, rbf_mu, rbf_sigma,
                                     W_edge, b_edge, W_node, ws, out);
    edge_kernel5<<<LL, 256, 0, stream>>>(P, w_out, ws, out);
}

// Round 13
// 100.772 us; speedup vs baseline: 1.0028x; 1.0028x over previous
//
#include <hip/hip_runtime.h>
#include <math.h>

#define LL 1024
#define DD 640
#define KK 32
#define MM 64
#define THRESH 0.2f
#define LOG2E 1.4426950408889634f

// ws layout (float units)
#define NPROJ_OFF  0                        // [1024][64] node_proj + b_edge (backbone base)
#define NPROJC_OFF (NPROJ_OFF + LL * MM)    // [1024][64] node_proj + b_edge + W0 (contact base)
#define WRT_OFF    (NPROJC_OFF + LL * MM)   // ushort[64][32]: bf16 W_edge[2+k][m], m-major
#define W1_OFF     (WRT_OFF + 1024)         // 64 f32
#define EA_OFF     (W1_OFF + MM)            // 32 f32 : -log2e/(2 sigma^2)
#define EB_OFF     (EA_OFF + KK)            // 32 f32 :  log2e*mu/sigma^2
#define EC_OFF     (EB_OFF + KK)            // 32 f32 : -log2e*mu^2/(2 sigma^2)
#define XYZ4_OFF   (EC_OFF + KK)            // [1024][4] padded coords

typedef float f32x4_t __attribute__((ext_vector_type(4)));
typedef short bf16x8_t __attribute__((ext_vector_type(8)));

union FragU { unsigned int u[4]; bf16x8_t v; };

#if __has_builtin(__builtin_amdgcn_sqrtf)
#define FSQRT __builtin_amdgcn_sqrtf
#else
#define FSQRT sqrtf
#endif

#if __has_builtin(__builtin_amdgcn_exp2f)
#define EXP2F __builtin_amdgcn_exp2f
#else
#define EXP2F(x) __expf((x) * 0.6931471805599453f)
#endif

__device__ __forceinline__ unsigned int pack_bf(float hi, float lo) {
    return __builtin_amdgcn_perm(__float_as_uint(hi), __float_as_uint(lo), 0x07060302u);
}

// Split-K node_proj GEMM (r10): 256 blocks, one 16x16 tile, 4 waves split K.
// Block 256 = constants + padded xyz table.
__global__ __launch_bounds__(256) void prep_sk(
    const float* __restrict__ S, const float* __restrict__ xyz,
    const float* __restrict__ rbf_mu, const float* __restrict__ rbf_sigma,
    const float* __restrict__ W_edge, const float* __restrict__ b_edge,
    const float* __restrict__ W_node, float* __restrict__ ws)
{
    const int b = blockIdx.x;
    const int t = threadIdx.x;
    if (b < 256) {
        __shared__ float red[4][64][4];
        const int lane = t & 63;
        const int wave = t >> 6;
        const int r0   = (b >> 2) * 16;     // row tile
        const int n0   = (b & 3) * 16;      // col tile
        const int col  = lane & 15;
        const int quad = lane >> 4;

        f32x4_t acc = {0.f, 0.f, 0.f, 0.f};
        const float* arow = S + (size_t)(r0 + col) * DD + wave * 160 + quad * 8;
        const float* bcol = W_node + (size_t)(wave * 160 + quad * 8) * MM + n0 + col;

        #pragma unroll
        for (int ks = 0; ks < 5; ++ks) {
            const float4 a0 = *(const float4*)(arow + ks * 32);
            const float4 a1 = *(const float4*)(arow + ks * 32 + 4);
            FragU A;
            A.u[0] = pack_bf(a0.y, a0.x); A.u[1] = pack_bf(a0.w, a0.z);
            A.u[2] = pack_bf(a1.y, a1.x); A.u[3] = pack_bf(a1.w, a1.z);
            const float* bk = bcol + (size_t)ks * 32 * MM;
            const float b0 = bk[0 * MM], b1 = bk[1 * MM], b2 = bk[2 * MM], b3 = bk[3 * MM];
            const float b4 = bk[4 * MM], b5 = bk[5 * MM], b6 = bk[6 * MM], b7 = bk[7 * MM];
            FragU B;
            B.u[0] = pack_bf(b1, b0); B.u[1] = pack_bf(b3, b2);
            B.u[2] = pack_bf(b5, b4); B.u[3] = pack_bf(b7, b6);
            acc = __builtin_amdgcn_mfma_f32_16x16x32_bf16(A.v, B.v, acc, 0, 0, 0);
        }
        red[wave][lane][0] = acc[0];
        red[wave][lane][1] = acc[1];
        red[wave][lane][2] = acc[2];
        red[wave][lane][3] = acc[3];
        __syncthreads();
        const int lr  = t & 63;
        const int reg = t >> 6;
        const float v = (red[0][lr][reg] + red[1][lr][reg])
                      + (red[2][lr][reg] + red[3][lr][reg]);
        const int row = r0 + (lr >> 4) * 4 + reg;
        const int cc  = n0 + (lr & 15);
        const float vb = v + b_edge[cc];
        ws[NPROJ_OFF  + (size_t)row * MM + cc] = vb;
        ws[NPROJC_OFF + (size_t)row * MM + cc] = vb + W_edge[cc];
    } else {
        unsigned short* wrt = (unsigned short*)(ws + WRT_OFF);
        if (t < MM) ws[W1_OFF + t] = W_edge[MM + t];
        if (t < KK) {
            const float s  = rbf_sigma[t];
            const float m_ = rbf_mu[t];
            const float inv = 1.0f / (2.0f * s * s);
            ws[EA_OFF + t] = -LOG2E * inv;
            ws[EB_OFF + t] =  2.0f * LOG2E * inv * m_;
            ws[EC_OFF + t] = -LOG2E * inv * m_ * m_;
        }
        for (int idx = t; idx < KK * MM; idx += 256) {
            const int m = idx >> 5, k = idx & 31;
            unsigned int u = __float_as_uint(W_edge[(2 + k) * MM + m]);
            u = (u + 0x7fffu + ((u >> 16) & 1u)) >> 16;   // RNE to bf16
            wrt[idx] = (unsigned short)u;
        }
        for (int n = t; n < LL; n += 256) {
            float4 v;
            v.x = xyz[3 * n + 0]; v.y = xyz[3 * n + 1];
            v.z = xyz[3 * n + 2]; v.w = 0.0f;
            *(float4*)(ws + XYZ4_OFF + 4 * n) = v;
        }
    }
}

// r10 edge body + xyz4 staged in LDS (16 KB/block; 4 blocks/CU unaffected).
__global__ __launch_bounds__(256) void edge_kernel6(
    const float* __restrict__ P, const float* __restrict__ w_out,
    const float* __restrict__ ws, float* __restrict__ out)
{
    const int tid  = threadIdx.x;
    const int lane = tid & 63;
    const int wave = tid >> 6;
    const int quad = lane >> 4;
    const int col  = lane & 15;
    __shared__ float4 lxyz[LL];       // 16 KB staged coord table
    __shared__ float sred[4][3];

    const float* __restrict__ nproj  = ws + NPROJ_OFF;
    const float* __restrict__ nprojc = ws + NPROJC_OFF;
    const float4* __restrict__ xyz4  = (const float4*)(ws + XYZ4_OFF);
    const unsigned short* __restrict__ wrt = (const unsigned short*)(ws + WRT_OFF);

    // cooperative LDS fill: 4 float4 per thread, coalesced
    #pragma unroll
    for (int n = tid; n < LL; n += 256) lxyz[n] = xyz4[n];

    // persistent frags
    FragU ar[4];
    float w1r[16], wvr[16];
    float aj[8], bj[8], cj[8];
    #pragma unroll
    for (int mt = 0; mt < 4; ++mt) {
        const uint4 w = *(const uint4*)(wrt + (mt * 16 + col) * KK + quad * 8);
        ar[mt].u[0] = w.x; ar[mt].u[1] = w.y; ar[mt].u[2] = w.z; ar[mt].u[3] = w.w;
        const f32x4_t w1 = *(const f32x4_t*)(ws + W1_OFF + mt * 16 + quad * 4);
        const f32x4_t wo = *(const f32x4_t*)(w_out + mt * 16 + quad * 4);
        #pragma unroll
        for (int r = 0; r < 4; ++r) { w1r[mt * 4 + r] = w1[r]; wvr[mt * 4 + r] = wo[r]; }
    }
    #pragma unroll
    for (int j = 0; j < 8; ++j) {
        aj[j] = ws[EA_OFF + quad * 8 + j];
        bj[j] = ws[EB_OFF + quad * 8 + j];
        cj[j] = ws[EC_OFF + quad * 8 + j];
    }
    __syncthreads();   // lxyz ready

    const int i = (int)blockIdx.x;
    const float4 xo = lxyz[i];
    const float xi0 = xo.x, xi1 = xo.y, xi2 = xo.z;
    const int len = (LL - 1) - i;
    float ax = 0.f, ay = 0.f, az = 0.f;
    const float* __restrict__ prow = P + (size_t)i * LL;

    for (int base = wave * 64; base < len; base += 256) {
        // own edge
        const int jo = base + lane;
        const bool valid = jo < len;
        const int jc_o = valid ? (i + 1 + jo) : (LL - 1);
        const float p_own = prow[jc_o];
        const float4 xj = lxyz[jc_o];
        const float rx = xj.x - xi0, ry = xj.y - xi1, rz = xj.z - xi2;
        const bool msk = valid && ((jo == 0) || ((jo >= 2) && (p_own > THRESH)));

        float res[4];
        #pragma unroll
        for (int ct = 0; ct < 4; ++ct) {
            const int jo_n = base + ct * 16 + col;
            int jc = i + 1 + jo_n;
            jc = (jc < LL) ? jc : (LL - 1);
            const float p_n = prow[jc];
            const float4 xn = lxyz[jc];
            const float dx = xn.x - xi0, dy = xn.y - xi1, dz = xn.z - xi2;
            const float q2 = fmaf(dx, dx, fmaf(dy, dy, fmaf(dz, dz, 1e-12f)));
            const float d_n = FSQRT(q2);
            const bool bb = (jo_n == 0);
            const float peff = bb ? 1.0f : p_n;
            const float* npr = (bb ? nproj : nprojc) + (size_t)jc * MM;

            float e[8];
            #pragma unroll
            for (int j = 0; j < 8; ++j)
                e[j] = EXP2F(fmaf(aj[j], q2, fmaf(bj[j], d_n, cj[j])));
            FragU bf;
            bf.u[0] = pack_bf(e[1], e[0]); bf.u[1] = pack_bf(e[3], e[2]);
            bf.u[2] = pack_bf(e[5], e[4]); bf.u[3] = pack_bf(e[7], e[6]);

            float g = 0.0f;
            #pragma unroll
            for (int mt = 0; mt < 4; ++mt) {
                f32x4_t c0 = *(const f32x4_t*)(npr + mt * 16 + quad * 4);
                c0[0] = fmaf(peff, w1r[mt*4+0], c0[0]);
                c0[1] = fmaf(peff, w1r[mt*4+1], c0[1]);
                c0[2] = fmaf(peff, w1r[mt*4+2], c0[2]);
                c0[3] = fmaf(peff, w1r[mt*4+3], c0[3]);
                c0 = __builtin_amdgcn_mfma_f32_16x16x32_bf16(ar[mt].v, bf.v, c0, 0, 0, 0);
                g = fmaf(fmaxf(c0[0], 0.f), wvr[mt*4+0], g);
                g = fmaf(fmaxf(c0[1], 0.f), wvr[mt*4+1], g);
                g = fmaf(fmaxf(c0[2], 0.f), wvr[mt*4+2], g);
                g = fmaf(fmaxf(c0[3], 0.f), wvr[mt*4+3], g);
            }
            g += __shfl_xor(g, 16, 64);
            g += __shfl_xor(g, 32, 64);
            res[ct] = g;
        }
        float gd = res[0];
        gd = (quad == 1) ? res[1] : gd;
        gd = (quad == 2) ? res[2] : gd;
        gd = (quad == 3) ? res[3] : gd;
        const float gate = msk ? (1.0f / (1.0f + __expf(-gd))) : 0.0f;
        ax = fmaf(gate, rx, ax);
        ay = fmaf(gate, ry, ay);
        az = fmaf(gate, rz, az);
    }

    #pragma unroll
    for (int off = 32; off > 0; off >>= 1) {
        ax += __shfl_down(ax, off, 64);
        ay += __shfl_down(ay, off, 64);
        az += __shfl_down(az, off, 64);
    }
    if (lane == 0) { sred[wave][0] = ax; sred[wave][1] = ay; sred[wave][2] = az; }
    __syncthreads();
    if (tid == 0) {
        const float tx = (sred[0][0] + sred[1][0]) + (sred[2][0] + sred[3][0]);
        const float ty = (sred[0][1] + sred[1][1]) + (sred[2][1] + sred[3][1]);
        const float tz = (sred[0][2] + sred[1][2]) + (sred[2][2] + sred[3][2]);
        out[i * 3 + 0] = xi0 + tx;
        out[i * 3 + 1] = xi1 + ty;
        out[i * 3 + 2] = xi2 + tz;
    }
}

extern "C" void kernel_launch(void* const* d_in, const int* in_sizes, int n_in,
                              void* d_out, int out_size, void* d_ws, size_t ws_size,
                              hipStream_t stream) {
    const float* S         = (const float*)d_in[0];
    const float* P         = (const float*)d_in[1];
    const float* xyz       = (const float*)d_in[2];
    const float* rbf_mu    = (const float*)d_in[3];
    const float* rbf_sigma = (const float*)d_in[4];
    const float* W_edge    = (const float*)d_in[5];
    const float* b_edge    = (const float*)d_in[6];
    const float* W_node    = (const float*)d_in[7];
    const float* w_out     = (const float*)d_in[8];
    float* out = (float*)d_out;
    float* ws  = (float*)d_ws;

    prep_sk<<<257, 256, 0, stream>>>(S, xyz, rbf_mu, rbf_sigma,
                                     W_edge, b_edge, W_node, ws);
    edge_kernel6<<<LL, 256, 0, stream>>>(P, w_out, ws, out);
}